// Round 3
// baseline (1381.439 us; speedup 1.0000x reference)
//
#include <hip/hip_runtime.h>
#include <hip/hip_bf16.h>

using bf16 = __hip_bfloat16;

typedef __bf16 bf16x8 __attribute__((ext_vector_type(8)));
typedef float  f32x4  __attribute__((ext_vector_type(4)));
typedef unsigned long long u64;
typedef unsigned short u16;

__device__ __forceinline__ float b2f(bf16 v) { return __bfloat162float(v); }
__device__ __forceinline__ bf16  f2b(float v) { return __float2bfloat16(v); }
__device__ __forceinline__ u16   bits(bf16 v) { return __builtin_bit_cast(u16, v); }

// ---------------------------------------------------------------------------
// Workspace layout
// ---------------------------------------------------------------------------
static constexpr size_t SZ_WD1S = 512ull  * 12288 * 2;  // bf16 [512][3*4096] (hi,lo,hi)
static constexpr size_t SZ_WD2S = 256ull  * 1536  * 2;  // bf16 [256][3*512]
static constexpr size_t SZ_WD3S = 128ull  * 768   * 2;  // bf16 [128][3*256]
static constexpr size_t SZ_WU1T = 256ull  * 128   * 2;  // bf16 [256][128]
static constexpr size_t SZ_WU2T = 512ull  * 256   * 2;  // bf16 [512][256]
static constexpr size_t SZ_WU3T = 4096ull * 512   * 2;  // bf16 [4096][512]
static constexpr size_t SZ_H1S  = 8192ull * 1536  * 2;  // bf16 [8192][3*512] (hi,hi,lo)
static constexpr size_t SZ_H2S  = 8192ull * 768   * 2;  // bf16 [8192][3*256]
static constexpr size_t SZ_LAT  = 8192ull * 128   * 4;  // f32
static constexpr size_t SZ_QEMB = 3ull * 8192 * 128 * 4;// f32
static constexpr size_t SZ_RL   = 8192ull * 128   * 2;  // bf16
static constexpr size_t SZ_U1   = 8192ull * 256   * 2;  // bf16
static constexpr size_t SZ_U2   = 8192ull * 512   * 2;  // bf16
static constexpr size_t SZ_CNRM = 768ull * 4;

static constexpr size_t OFF_WD1S = 0;
static constexpr size_t OFF_WD2S = OFF_WD1S + SZ_WD1S;
static constexpr size_t OFF_WD3S = OFF_WD2S + SZ_WD2S;
static constexpr size_t OFF_WU1T = OFF_WD3S + SZ_WD3S;
static constexpr size_t OFF_WU2T = OFF_WU1T + SZ_WU1T;
static constexpr size_t OFF_WU3T = OFF_WU2T + SZ_WU2T;
static constexpr size_t OFF_H1S  = OFF_WU3T + SZ_WU3T;
static constexpr size_t OFF_H2S  = OFF_H1S  + SZ_H1S;
static constexpr size_t OFF_LAT  = OFF_H2S  + SZ_H2S;
static constexpr size_t OFF_QEMB = OFF_LAT  + SZ_LAT;
static constexpr size_t OFF_RL   = OFF_QEMB + SZ_QEMB;
static constexpr size_t OFF_U1   = OFF_RL   + SZ_RL;
static constexpr size_t OFF_U2   = OFF_U1   + SZ_U1;
static constexpr size_t OFF_CNRM = OFF_U2   + SZ_U2;
static constexpr size_t OFF_STAT = OFF_CNRM + ((SZ_CNRM + 255) & ~size_t(255));
// stats (memset 0 each launch): +0 f32 commit; +8 double gram[6]; +64 f32 meanAcc[384]

// ---------------------------------------------------------------------------
// Weight transposes: in [K][N] f32.
// ---------------------------------------------------------------------------
__global__ void wtrans_bf16(const float* __restrict__ in, bf16* __restrict__ out,
                            int K, int N)
{
    __shared__ float tile[32][33];
    const int tx = threadIdx.x, ty = threadIdx.y;
    const int n0 = blockIdx.x * 32, k0 = blockIdx.y * 32;
    #pragma unroll
    for (int i = 0; i < 32; i += 8)
        tile[ty + i][tx] = in[(size_t)(k0 + ty + i) * N + n0 + tx];
    __syncthreads();
    #pragma unroll
    for (int i = 0; i < 32; i += 8)
        out[(size_t)(n0 + ty + i) * K + k0 + tx] = f2b(tile[tx][ty + i]);
}

__global__ void wtrans_split3(const float* __restrict__ in, bf16* __restrict__ out,
                              int K, int N)
{
    __shared__ float tile[32][33];
    const int tx = threadIdx.x, ty = threadIdx.y;
    const int n0 = blockIdx.x * 32, k0 = blockIdx.y * 32;
    #pragma unroll
    for (int i = 0; i < 32; i += 8)
        tile[ty + i][tx] = in[(size_t)(k0 + ty + i) * N + n0 + tx];
    __syncthreads();
    #pragma unroll
    for (int i = 0; i < 32; i += 8) {
        const float v = tile[tx][ty + i];
        const bf16 hi = f2b(v);
        const bf16 lo = f2b(v - b2f(hi));
        bf16* o = out + (size_t)(n0 + ty + i) * 3 * K + 3 * (k0 + tx);
        o[0] = hi; o[1] = lo; o[2] = hi;
    }
}

__global__ void cnorm_kernel(const float* __restrict__ cb, float* __restrict__ cnorm)
{
    const int i = blockIdx.x * blockDim.x + threadIdx.x;
    if (i < 768) {
        float s = 0.f;
        for (int k = 0; k < 32; ++k) { const float v = cb[i * 32 + k]; s += v * v; }
        cnorm[i] = s;
    }
}

// ---------------------------------------------------------------------------
// Layer-1 GEMM with on-the-fly 3-term split of A = x (f32).
// ---------------------------------------------------------------------------
__global__ __launch_bounds__(256)
void gemm1_x3(const float* __restrict__ A, const bf16* __restrict__ Bs3,
              const float* __restrict__ bias, bf16* __restrict__ out)
{
    __shared__ bf16 As[128 * 96];
    __shared__ bf16 Bs[128 * 96];
    const int t = threadIdx.x, lane = t & 63, w = t >> 6;
    const int n0 = blockIdx.x * 128;     // N=512 -> grid.x = 4
    const int m0 = blockIdx.y * 128;
    const int wr = w >> 1, wc = w & 1, l15 = lane & 15, quad = lane >> 4;

    f32x4 acc[4][4];
    #pragma unroll
    for (int i = 0; i < 4; ++i)
        #pragma unroll
        for (int j = 0; j < 4; ++j)
            #pragma unroll
            for (int r = 0; r < 4; ++r) acc[i][j][r] = 0.f;

    for (int ko = 0; ko < 4096; ko += 32) {
        #pragma unroll
        for (int i = 0; i < 6; ++i) {
            const int c   = i * 256 + t;
            const int row = c / 12;
            const int cc  = c - row * 12;
            const bf16* gb = Bs3 + (size_t)(n0 + row) * 12288 + ko * 3 + cc * 8;
            __builtin_amdgcn_global_load_lds(
                (const __attribute__((address_space(1))) void*)gb,
                (__attribute__((address_space(3))) void*)(Bs + (size_t)c * 8), 16, 0, 0);
        }
        #pragma unroll
        for (int i = 0; i < 4; ++i) {
            const int c = i * 256 + t;
            const int row = c >> 3, c4 = c & 7;
            const float4 v = *(const float4*)(A + (size_t)(m0 + row) * 4096 + ko + c4 * 4);
            const float va[4] = {v.x, v.y, v.z, v.w};
            u64 h[4], l[4];
            #pragma unroll
            for (int j = 0; j < 4; ++j) {
                const bf16 hh = f2b(va[j]);
                h[j] = bits(hh);
                l[j] = bits(f2b(va[j] - b2f(hh)));
            }
            const u64 p0 = h[0] | (h[0] << 16) | (l[0] << 32) | (h[1] << 48);
            const u64 p1 = h[1] | (l[1] << 16) | (h[2] << 32) | (h[2] << 48);
            const u64 p2 = l[2] | (h[3] << 16) | (h[3] << 32) | (l[3] << 48);
            u64* dst = (u64*)(As + (size_t)row * 96 + c4 * 12);
            dst[0] = p0; dst[1] = p1; dst[2] = p2;
        }
        __syncthreads();
        #pragma unroll
        for (int kk = 0; kk < 3; ++kk) {
            bf16x8 af[4], bfr[4];
            #pragma unroll
            for (int mi = 0; mi < 4; ++mi)
                af[mi] = *(const bf16x8*)(As + (wr * 64 + mi * 16 + l15) * 96 + kk * 32 + quad * 8);
            #pragma unroll
            for (int ni = 0; ni < 4; ++ni)
                bfr[ni] = *(const bf16x8*)(Bs + (wc * 64 + ni * 16 + l15) * 96 + kk * 32 + quad * 8);
            #pragma unroll
            for (int mi = 0; mi < 4; ++mi)
                #pragma unroll
                for (int ni = 0; ni < 4; ++ni)
                    acc[mi][ni] = __builtin_amdgcn_mfma_f32_16x16x32_bf16(
                        af[mi], bfr[ni], acc[mi][ni], 0, 0, 0);
        }
        __syncthreads();
    }

    #pragma unroll
    for (int mi = 0; mi < 4; ++mi)
        #pragma unroll
        for (int ni = 0; ni < 4; ++ni) {
            const int col = n0 + wc * 64 + ni * 16 + l15;
            const float bv = bias[col];
            #pragma unroll
            for (int r = 0; r < 4; ++r) {
                const int row = m0 + wr * 64 + mi * 16 + quad * 4 + r;
                float v = acc[mi][ni][r] + bv;
                v = v > 0.f ? v : 0.f;
                const bf16 hi = f2b(v);
                const bf16 lo = f2b(v - b2f(hi));
                bf16* o = out + (size_t)row * 1536 + 3 * col;
                o[0] = hi; o[1] = hi; o[2] = lo;
            }
        }
}

// ---------------------------------------------------------------------------
// Generic bf16 MFMA GEMM. EPI: 0 = f32 out; 1 = split3 bf16 (hi,hi,lo, ldc=3N);
// 2 = bf16 out; 3 = f32 out with clip[-1,1].  Grid: (N/128, M/128).
// ---------------------------------------------------------------------------
template <int EPI, int RELU>
__global__ __launch_bounds__(256)
void gemm_bt(const bf16* __restrict__ A, const bf16* __restrict__ Bt,
             const float* __restrict__ bias, void* __restrict__ outp,
             int M, int N, int K)
{
    __shared__ bf16 As[128 * 64];
    __shared__ bf16 Bs[128 * 64];
    const int t = threadIdx.x, lane = t & 63, w = t >> 6;
    const int n0 = blockIdx.x * 128;
    const int m0 = blockIdx.y * 128;
    const int wr = w >> 1, wc = w & 1, l15 = lane & 15, quad = lane >> 4;

    f32x4 acc[4][4];
    #pragma unroll
    for (int i = 0; i < 4; ++i)
        #pragma unroll
        for (int j = 0; j < 4; ++j)
            #pragma unroll
            for (int r = 0; r < 4; ++r) acc[i][j][r] = 0.f;

    for (int k0 = 0; k0 < K; k0 += 64) {
        #pragma unroll
        for (int i = 0; i < 4; ++i) {
            const int c   = i * 256 + t;
            const int row = c >> 3;
            const int col = (c & 7) * 8;
            const bf16* ga = A  + (size_t)(m0 + row) * K + k0 + col;
            const bf16* gb = Bt + (size_t)(n0 + row) * K + k0 + col;
            __builtin_amdgcn_global_load_lds(
                (const __attribute__((address_space(1))) void*)ga,
                (__attribute__((address_space(3))) void*)(As + (size_t)c * 8), 16, 0, 0);
            __builtin_amdgcn_global_load_lds(
                (const __attribute__((address_space(1))) void*)gb,
                (__attribute__((address_space(3))) void*)(Bs + (size_t)c * 8), 16, 0, 0);
        }
        __syncthreads();
        #pragma unroll
        for (int kk = 0; kk < 2; ++kk) {
            bf16x8 af[4], bfr[4];
            #pragma unroll
            for (int mi = 0; mi < 4; ++mi)
                af[mi] = *(const bf16x8*)(As + (wr * 64 + mi * 16 + l15) * 64 + kk * 32 + quad * 8);
            #pragma unroll
            for (int ni = 0; ni < 4; ++ni)
                bfr[ni] = *(const bf16x8*)(Bs + (wc * 64 + ni * 16 + l15) * 64 + kk * 32 + quad * 8);
            #pragma unroll
            for (int mi = 0; mi < 4; ++mi)
                #pragma unroll
                for (int ni = 0; ni < 4; ++ni)
                    acc[mi][ni] = __builtin_amdgcn_mfma_f32_16x16x32_bf16(
                        af[mi], bfr[ni], acc[mi][ni], 0, 0, 0);
        }
        __syncthreads();
    }

    #pragma unroll
    for (int mi = 0; mi < 4; ++mi)
        #pragma unroll
        for (int ni = 0; ni < 4; ++ni) {
            const int col = n0 + wc * 64 + ni * 16 + l15;
            const float bv = bias[col];
            #pragma unroll
            for (int r = 0; r < 4; ++r) {
                const int row = m0 + wr * 64 + mi * 16 + quad * 4 + r;
                float v = acc[mi][ni][r] + bv;
                if (RELU) v = v > 0.f ? v : 0.f;
                if (EPI == 0) {
                    ((float*)outp)[(size_t)row * N + col] = v;
                } else if (EPI == 1) {
                    const bf16 hi = f2b(v);
                    const bf16 lo = f2b(v - b2f(hi));
                    bf16* o = (bf16*)outp + (size_t)row * 3 * N + 3 * col;
                    o[0] = hi; o[1] = hi; o[2] = lo;
                } else if (EPI == 2) {
                    ((bf16*)outp)[(size_t)row * N + col] = f2b(v);
                } else {
                    v = fminf(fmaxf(v, -1.f), 1.f);
                    ((float*)outp)[(size_t)row * N + col] = v;   // f32 recon
                }
            }
        }
}

// ---------------------------------------------------------------------------
// VQ (all f32). idx written as f32 values.
// ---------------------------------------------------------------------------
__global__ __launch_bounds__(256)
void vq_kernel(const float* __restrict__ latent,
               const float* __restrict__ Win,  const float* __restrict__ bin_,
               const float* __restrict__ cb,   const float* __restrict__ cnorm,
               const float* __restrict__ Wout, const float* __restrict__ bout,
               float* __restrict__ qemb, bf16* __restrict__ rl,
               float* __restrict__ idx_out, float* __restrict__ commit_acc)
{
    __shared__ float lat_s[4][128];
    __shared__ float xe_s[4][3][32];
    __shared__ float q_s[4][3][32];
    __shared__ int   idx_s[4][3];
    __shared__ float commit_s;

    const int t = threadIdx.x, lane = t & 63, w = t >> 6;
    if (t == 0) commit_s = 0.f;

    for (int it = 0; it < 8; ++it) {
        const int rbase = it * 1024 + blockIdx.x * 4;
        __syncthreads();
        for (int j = t; j < 4 * 128; j += 256) {
            const int r4 = j >> 7, h = j & 127;
            lat_s[r4][h] = latent[(size_t)(rbase + r4) * 128 + h];
        }
        __syncthreads();
        for (int j = t; j < 4 * 96; j += 256) {
            const int r4 = j / 96, rem = j % 96, e = rem >> 5, c = rem & 31;
            float s = bin_[e * 32 + c];
            const float* wp = Win + (size_t)e * 128 * 32 + c;
            #pragma unroll 4
            for (int h = 0; h < 128; ++h) s += lat_s[r4][h] * wp[h * 32];
            xe_s[r4][e][c] = s;
        }
        __syncthreads();
        for (int e = 0; e < 3; ++e) {
            const int r4 = w;
            float best = 1e30f; int bidx = 0;
            const float* cbe = cb + (size_t)e * 256 * 32;
            #pragma unroll
            for (int ci = 0; ci < 4; ++ci) {
                const int code = ci * 64 + lane;
                const float* cp = cbe + (size_t)code * 32;
                float dot = 0.f;
                #pragma unroll
                for (int k = 0; k < 32; ++k) dot += xe_s[r4][e][k] * cp[k];
                const float d = cnorm[e * 256 + code] - 2.f * dot;
                if (d < best || (d == best && code < bidx)) { best = d; bidx = code; }
            }
            for (int off = 32; off; off >>= 1) {
                const float ob = __shfl_down(best, off, 64);
                const int   oi = __shfl_down(bidx, off, 64);
                if (ob < best || (ob == best && oi < bidx)) { best = ob; bidx = oi; }
            }
            if (lane == 0) {
                idx_s[r4][e] = bidx;
                idx_out[(size_t)(rbase + r4) * 3 + e] = (float)bidx;
            }
        }
        __syncthreads();
        for (int j = t; j < 4 * 96; j += 256) {
            const int r4 = j / 96, rem = j % 96, e = rem >> 5, c = rem & 31;
            const float qv = cb[((size_t)e * 256 + idx_s[r4][e]) * 32 + c];
            q_s[r4][e][c] = qv;
            const float d = qv - xe_s[r4][e][c];
            atomicAdd(&commit_s, d * d);
        }
        __syncthreads();
        for (int j = t; j < 4 * 128; j += 256) {
            const int r4 = j >> 7, h = j & 127;
            const int r = rbase + r4;
            float s3 = 0.f;
            #pragma unroll
            for (int e = 0; e < 3; ++e) {
                float s = bout[e * 128 + h];
                const float* wp = Wout + (size_t)e * 32 * 128 + h;
                #pragma unroll
                for (int c = 0; c < 32; ++c) s += q_s[r4][e][c] * wp[c * 128];
                qemb[((size_t)e * 8192 + r) * 128 + h] = s;
                s3 += s;
            }
            rl[(size_t)r * 128 + h] = f2b(s3 * (1.f / 3.f));
        }
    }
    __syncthreads();
    if (t == 0) atomicAdd(commit_acc, commit_s);
}

__global__ __launch_bounds__(256)
void mean_kernel(const float* __restrict__ qemb, float* __restrict__ meanAcc)
{
    const int e = blockIdx.x / 32;
    const int b0 = (blockIdx.x % 32) * 256;
    const int t = threadIdx.x;
    const int h = t & 127, half = t >> 7;
    float s = 0.f;
    for (int b = b0 + half; b < b0 + 256; b += 2)
        s += qemb[((size_t)e * 8192 + b) * 128 + h];
    __shared__ float red[256];
    red[t] = s;
    __syncthreads();
    if (t < 128) atomicAdd(&meanAcc[e * 128 + h], red[t] + red[t + 128]);
}

__global__ __launch_bounds__(256)
void gram_kernel(const float* __restrict__ qemb, const float* __restrict__ meanAcc,
                 double* __restrict__ gram)
{
    const int t = threadIdx.x;
    const int h = t & 127, half = t >> 7;
    const int b0 = blockIdx.x * 128;
    const float m0 = meanAcc[0 * 128 + h] * (1.f / 8192.f);
    const float m1 = meanAcc[1 * 128 + h] * (1.f / 8192.f);
    const float m2 = meanAcc[2 * 128 + h] * (1.f / 8192.f);
    float g[6] = {0, 0, 0, 0, 0, 0};
    for (int b = b0 + half; b < b0 + 128; b += 2) {
        const float v0 = qemb[((size_t)0 * 8192 + b) * 128 + h] - m0;
        const float v1 = qemb[((size_t)1 * 8192 + b) * 128 + h] - m1;
        const float v2 = qemb[((size_t)2 * 8192 + b) * 128 + h] - m2;
        g[0] += v0 * v0; g[1] += v0 * v1; g[2] += v0 * v2;
        g[3] += v1 * v1; g[4] += v1 * v2; g[5] += v2 * v2;
    }
    __shared__ float red[256];
    for (int i = 0; i < 6; ++i) {
        red[t] = g[i];
        __syncthreads();
        for (int o = 128; o; o >>= 1) { if (t < o) red[t] += red[t + o]; __syncthreads(); }
        if (t == 0) atomicAdd(&gram[i], (double)red[0]);
        __syncthreads();
    }
}

__global__ void final_kernel(const float* __restrict__ commit_acc,
                             const double* __restrict__ gram,
                             float* __restrict__ out2)
{
    if (threadIdx.x != 0 || blockIdx.x != 0) return;
    const double denom = 8192.0 * 128.0 - 1.0;
    const double c00 = gram[0] / denom, c01 = gram[1] / denom, c02 = gram[2] / denom;
    const double c11 = gram[3] / denom, c12 = gram[4] / denom, c22 = gram[5] / denom;
    double s0 = sqrt(c00), s1 = sqrt(c11), s2 = sqrt(c22);
    if (!(s0 > 1e-8)) s0 = 1.0;
    if (!(s1 > 1e-8)) s1 = 1.0;
    if (!(s2 > 1e-8)) s2 = 1.0;
    const double r01 = c01 / (s0 * s1), r02 = c02 / (s0 * s2), r12 = c12 / (s1 * s2);
    const double decorr = 2.0 * (r01 * r01 + r02 * r02 + r12 * r12);
    out2[0] = (float)((double)commit_acc[0] * (0.25 / (8192.0 * 32.0)));
    out2[1] = (float)decorr;
}

// ---------------------------------------------------------------------------
extern "C" void kernel_launch(void* const* d_in, const int* in_sizes, int n_in,
                              void* d_out, int out_size, void* d_ws, size_t ws_size,
                              hipStream_t stream)
{
    const float* x    = (const float*)d_in[0];
    const float* Wd1  = (const float*)d_in[1];
    const float* bd1  = (const float*)d_in[2];
    const float* Wd2  = (const float*)d_in[3];
    const float* bd2  = (const float*)d_in[4];
    const float* Wd3  = (const float*)d_in[5];
    const float* bd3  = (const float*)d_in[6];
    const float* Win  = (const float*)d_in[7];
    const float* bin_ = (const float*)d_in[8];
    const float* cb   = (const float*)d_in[9];
    const float* Wout = (const float*)d_in[10];
    const float* bout = (const float*)d_in[11];
    const float* Wu1  = (const float*)d_in[12];
    const float* bu1  = (const float*)d_in[13];
    const float* Wu2  = (const float*)d_in[14];
    const float* bu2  = (const float*)d_in[15];
    const float* Wu3  = (const float*)d_in[16];
    const float* bu3  = (const float*)d_in[17];

    char* ws = (char*)d_ws;
    bf16*  Wd1s   = (bf16*)(ws + OFF_WD1S);
    bf16*  Wd2s   = (bf16*)(ws + OFF_WD2S);
    bf16*  Wd3s   = (bf16*)(ws + OFF_WD3S);
    bf16*  Wu1T   = (bf16*)(ws + OFF_WU1T);
    bf16*  Wu2T   = (bf16*)(ws + OFF_WU2T);
    bf16*  Wu3T   = (bf16*)(ws + OFF_WU3T);
    bf16*  h1s    = (bf16*)(ws + OFF_H1S);
    bf16*  h2s    = (bf16*)(ws + OFF_H2S);
    float* latent = (float*)(ws + OFF_LAT);
    float* qemb   = (float*)(ws + OFF_QEMB);
    bf16*  rl     = (bf16*)(ws + OFF_RL);
    bf16*  u1     = (bf16*)(ws + OFF_U1);
    bf16*  u2     = (bf16*)(ws + OFF_U2);
    float* cnorm  = (float*)(ws + OFF_CNRM);
    float* commit = (float*)(ws + OFF_STAT);
    double* gram  = (double*)(ws + OFF_STAT + 8);
    float* meanA  = (float*)(ws + OFF_STAT + 64);

    float* out_f   = (float*)d_out;                       // f32 outputs
    float* idx_out = out_f + (size_t)8192 * 4096;
    float* scal    = idx_out + (size_t)8192 * 3;

    hipMemsetAsync(ws + OFF_STAT, 0, 2048, stream);

    const dim3 tb(32, 8);
    wtrans_split3<<<dim3(16, 128), tb, 0, stream>>>(Wd1, Wd1s, 4096, 512);
    wtrans_split3<<<dim3(8, 16),   tb, 0, stream>>>(Wd2, Wd2s, 512, 256);
    wtrans_split3<<<dim3(4, 8),    tb, 0, stream>>>(Wd3, Wd3s, 256, 128);
    wtrans_bf16<<<dim3(8, 4),      tb, 0, stream>>>(Wu1, Wu1T, 128, 256);
    wtrans_bf16<<<dim3(16, 8),     tb, 0, stream>>>(Wu2, Wu2T, 256, 512);
    wtrans_bf16<<<dim3(128, 16),   tb, 0, stream>>>(Wu3, Wu3T, 512, 4096);
    cnorm_kernel<<<3, 256, 0, stream>>>(cb, cnorm);

    // down MLP: 3-term split bf16 (~f32 accuracy for the argmin)
    gemm1_x3<<<dim3(4, 64), 256, 0, stream>>>(x, Wd1s, bd1, h1s);
    gemm_bt<1, 1><<<dim3(2, 64), 256, 0, stream>>>(h1s, Wd2s, bd2, h2s,    8192, 256, 1536);
    gemm_bt<0, 0><<<dim3(1, 64), 256, 0, stream>>>(h2s, Wd3s, bd3, latent, 8192, 128, 768);

    vq_kernel<<<256, 256, 0, stream>>>(latent, Win, bin_, cb, cnorm, Wout, bout,
                                       qemb, rl, idx_out, commit);
    mean_kernel<<<96, 256, 0, stream>>>(qemb, meanA);
    gram_kernel<<<64, 256, 0, stream>>>(qemb, meanA, gram);
    final_kernel<<<1, 64, 0, stream>>>(commit, gram, scal);

    // up MLP: plain bf16 compute, f32 recon out
    gemm_bt<2, 1><<<dim3(2, 64),  256, 0, stream>>>(rl, Wu1T, bu1, u1,     8192, 256,  128);
    gemm_bt<2, 1><<<dim3(4, 64),  256, 0, stream>>>(u1, Wu2T, bu2, u2,     8192, 512,  256);
    gemm_bt<3, 0><<<dim3(32, 64), 256, 0, stream>>>(u2, Wu3T, bu3, out_f,  8192, 4096, 512);

    (void)in_sizes; (void)n_in; (void)out_size; (void)ws_size;
}

// Round 4
// 816.040 us; speedup vs baseline: 1.6929x; 1.6929x over previous
//
#include <hip/hip_runtime.h>
#include <hip/hip_bf16.h>

using bf16 = __hip_bfloat16;

typedef __bf16 bf16x8 __attribute__((ext_vector_type(8)));
typedef float  f32x4  __attribute__((ext_vector_type(4)));
typedef unsigned long long u64;
typedef unsigned short u16;
typedef unsigned int u32;

__device__ __forceinline__ float b2f(bf16 v) { return __bfloat162float(v); }
__device__ __forceinline__ bf16  f2b(float v) { return __float2bfloat16(v); }
__device__ __forceinline__ u16   bits(bf16 v) { return __builtin_bit_cast(u16, v); }

// ---------------------------------------------------------------------------
// Workspace layout
// ---------------------------------------------------------------------------
static constexpr size_t SZ_WD1S = 512ull  * 12288 * 2;  // bf16 [512][3*4096] (hi,lo,hi)
static constexpr size_t SZ_WD2S = 256ull  * 1536  * 2;  // bf16 [256][3*512]
static constexpr size_t SZ_WFUS = 128ull  * 768   * 2;  // bf16 [128][3*256] (Wd3@Win fused, split3)
static constexpr size_t SZ_WU1T = 256ull  * 128   * 2;
static constexpr size_t SZ_WU2T = 512ull  * 256   * 2;
static constexpr size_t SZ_WU3T = 4096ull * 512   * 2;
static constexpr size_t SZ_H1S  = 8192ull * 1536  * 2;  // bf16 [8192][3*512] (hi,hi,lo)
static constexpr size_t SZ_H2S  = 8192ull * 768   * 2;  // bf16 [8192][3*256]
static constexpr size_t SZ_XE   = 8192ull * 128   * 4;  // f32 xe (cols e*32+c, 96..127 unused)
static constexpr size_t SZ_QEMB = 3ull * 8192 * 128 * 4;// f32
static constexpr size_t SZ_RL   = 8192ull * 128   * 2;  // bf16
static constexpr size_t SZ_U1   = 8192ull * 256   * 2;
static constexpr size_t SZ_U2   = 8192ull * 512   * 2;
static constexpr size_t SZ_CNRM = 768ull * 4;
static constexpr size_t SZ_BFUS = 128ull * 4;

static constexpr size_t OFF_WD1S = 0;
static constexpr size_t OFF_WD2S = OFF_WD1S + SZ_WD1S;
static constexpr size_t OFF_WFUS = OFF_WD2S + SZ_WD2S;
static constexpr size_t OFF_WU1T = OFF_WFUS + SZ_WFUS;
static constexpr size_t OFF_WU2T = OFF_WU1T + SZ_WU1T;
static constexpr size_t OFF_WU3T = OFF_WU2T + SZ_WU2T;
static constexpr size_t OFF_H1S  = OFF_WU3T + SZ_WU3T;
static constexpr size_t OFF_H2S  = OFF_H1S  + SZ_H1S;
static constexpr size_t OFF_XE   = OFF_H2S  + SZ_H2S;
static constexpr size_t OFF_QEMB = OFF_XE   + SZ_XE;
static constexpr size_t OFF_RL   = OFF_QEMB + SZ_QEMB;
static constexpr size_t OFF_U1   = OFF_RL   + SZ_RL;
static constexpr size_t OFF_U2   = OFF_U1   + SZ_U1;
static constexpr size_t OFF_CNRM = OFF_U2   + SZ_U2;
static constexpr size_t OFF_BFUS = OFF_CNRM + ((SZ_CNRM + 255) & ~size_t(255));
static constexpr size_t OFF_STAT = OFF_BFUS + ((SZ_BFUS + 255) & ~size_t(255));
// stats (memset 0 each launch): +0 f32 commit; +8 double gram[6]; +64 f32 meanAcc[384]

// ---------------------------------------------------------------------------
// Weight transposes: in [K][N] f32.
// ---------------------------------------------------------------------------
__global__ void wtrans_bf16(const float* __restrict__ in, bf16* __restrict__ out,
                            int K, int N)
{
    __shared__ float tile[32][33];
    const int tx = threadIdx.x, ty = threadIdx.y;
    const int n0 = blockIdx.x * 32, k0 = blockIdx.y * 32;
    #pragma unroll
    for (int i = 0; i < 32; i += 8)
        tile[ty + i][tx] = in[(size_t)(k0 + ty + i) * N + n0 + tx];
    __syncthreads();
    #pragma unroll
    for (int i = 0; i < 32; i += 8)
        out[(size_t)(n0 + ty + i) * K + k0 + tx] = f2b(tile[tx][ty + i]);
}

__global__ void wtrans_split3(const float* __restrict__ in, bf16* __restrict__ out,
                              int K, int N)
{
    __shared__ float tile[32][33];
    const int tx = threadIdx.x, ty = threadIdx.y;
    const int n0 = blockIdx.x * 32, k0 = blockIdx.y * 32;
    #pragma unroll
    for (int i = 0; i < 32; i += 8)
        tile[ty + i][tx] = in[(size_t)(k0 + ty + i) * N + n0 + tx];
    __syncthreads();
    #pragma unroll
    for (int i = 0; i < 32; i += 8) {
        const float v = tile[tx][ty + i];
        const bf16 hi = f2b(v);
        const bf16 lo = f2b(v - b2f(hi));
        bf16* o = out + (size_t)(n0 + ty + i) * 3 * K + 3 * (k0 + tx);
        o[0] = hi; o[1] = lo; o[2] = hi;
    }
}

__global__ void cnorm_kernel(const float* __restrict__ cb, float* __restrict__ cnorm)
{
    const int i = blockIdx.x * blockDim.x + threadIdx.x;
    if (i < 768) {
        float s = 0.f;
        for (int k = 0; k < 32; ++k) { const float v = cb[i * 32 + k]; s += v * v; }
        cnorm[i] = s;
    }
}

// ---------------------------------------------------------------------------
// Fused VQ projection weights: Wfuse[n=e*32+c][d2] = sum_h Wd3[d2][h]*Win[e][h][c]
// emitted split3 (hi,lo,hi) as B-side for gemm_bt; rows 96..127 zero.
// bfuse[n] = sum_h bd3[h]*Win[e][h][c] + bin[e][c].
// ---------------------------------------------------------------------------
__global__ __launch_bounds__(256)
void wfuse_kernel(const float* __restrict__ Wd3, const float* __restrict__ bd3,
                  const float* __restrict__ Win, const float* __restrict__ bin_,
                  bf16* __restrict__ BtS, float* __restrict__ bfuse)
{
    const int n = blockIdx.x;       // 0..127
    const int t = threadIdx.x;      // 0..255 == d2
    if (n >= 96) {
        bf16* o = BtS + (size_t)n * 768 + 3 * t;
        o[0] = f2b(0.f); o[1] = f2b(0.f); o[2] = f2b(0.f);
        if (t == 0) bfuse[n] = 0.f;
        return;
    }
    const int e = n >> 5, c = n & 31;
    float s = 0.f;
    for (int h = 0; h < 128; ++h)
        s += Wd3[t * 128 + h] * Win[(size_t)(e * 128 + h) * 32 + c];
    const bf16 hi = f2b(s);
    const bf16 lo = f2b(s - b2f(hi));
    bf16* o = BtS + (size_t)n * 768 + 3 * t;
    o[0] = hi; o[1] = lo; o[2] = hi;
    if (t == 0) {
        float b = bin_[e * 32 + c];
        for (int h = 0; h < 128; ++h)
            b += bd3[h] * Win[(size_t)(e * 128 + h) * 32 + c];
        bfuse[n] = b;
    }
}

// ---------------------------------------------------------------------------
// Layer-1 GEMM with on-the-fly 3-term split of A = x (f32).
// ---------------------------------------------------------------------------
__global__ __launch_bounds__(256)
void gemm1_x3(const float* __restrict__ A, const bf16* __restrict__ Bs3,
              const float* __restrict__ bias, bf16* __restrict__ out)
{
    __shared__ bf16 As[128 * 96];
    __shared__ bf16 Bs[128 * 96];
    const int t = threadIdx.x, lane = t & 63, w = t >> 6;
    const int n0 = blockIdx.x * 128;
    const int m0 = blockIdx.y * 128;
    const int wr = w >> 1, wc = w & 1, l15 = lane & 15, quad = lane >> 4;

    f32x4 acc[4][4];
    #pragma unroll
    for (int i = 0; i < 4; ++i)
        #pragma unroll
        for (int j = 0; j < 4; ++j)
            #pragma unroll
            for (int r = 0; r < 4; ++r) acc[i][j][r] = 0.f;

    for (int ko = 0; ko < 4096; ko += 32) {
        #pragma unroll
        for (int i = 0; i < 6; ++i) {
            const int c   = i * 256 + t;
            const int row = c / 12;
            const int cc  = c - row * 12;
            const bf16* gb = Bs3 + (size_t)(n0 + row) * 12288 + ko * 3 + cc * 8;
            __builtin_amdgcn_global_load_lds(
                (const __attribute__((address_space(1))) void*)gb,
                (__attribute__((address_space(3))) void*)(Bs + (size_t)c * 8), 16, 0, 0);
        }
        #pragma unroll
        for (int i = 0; i < 4; ++i) {
            const int c = i * 256 + t;
            const int row = c >> 3, c4 = c & 7;
            const float4 v = *(const float4*)(A + (size_t)(m0 + row) * 4096 + ko + c4 * 4);
            const float va[4] = {v.x, v.y, v.z, v.w};
            u64 h[4], l[4];
            #pragma unroll
            for (int j = 0; j < 4; ++j) {
                const bf16 hh = f2b(va[j]);
                h[j] = bits(hh);
                l[j] = bits(f2b(va[j] - b2f(hh)));
            }
            const u64 p0 = h[0] | (h[0] << 16) | (l[0] << 32) | (h[1] << 48);
            const u64 p1 = h[1] | (l[1] << 16) | (h[2] << 32) | (h[2] << 48);
            const u64 p2 = l[2] | (h[3] << 16) | (h[3] << 32) | (l[3] << 48);
            u64* dst = (u64*)(As + (size_t)row * 96 + c4 * 12);
            dst[0] = p0; dst[1] = p1; dst[2] = p2;
        }
        __syncthreads();
        #pragma unroll
        for (int kk = 0; kk < 3; ++kk) {
            bf16x8 af[4], bfr[4];
            #pragma unroll
            for (int mi = 0; mi < 4; ++mi)
                af[mi] = *(const bf16x8*)(As + (wr * 64 + mi * 16 + l15) * 96 + kk * 32 + quad * 8);
            #pragma unroll
            for (int ni = 0; ni < 4; ++ni)
                bfr[ni] = *(const bf16x8*)(Bs + (wc * 64 + ni * 16 + l15) * 96 + kk * 32 + quad * 8);
            #pragma unroll
            for (int mi = 0; mi < 4; ++mi)
                #pragma unroll
                for (int ni = 0; ni < 4; ++ni)
                    acc[mi][ni] = __builtin_amdgcn_mfma_f32_16x16x32_bf16(
                        af[mi], bfr[ni], acc[mi][ni], 0, 0, 0);
        }
        __syncthreads();
    }

    #pragma unroll
    for (int mi = 0; mi < 4; ++mi)
        #pragma unroll
        for (int ni = 0; ni < 4; ++ni) {
            const int col = n0 + wc * 64 + ni * 16 + l15;
            const float bv = bias[col];
            #pragma unroll
            for (int r = 0; r < 4; ++r) {
                const int row = m0 + wr * 64 + mi * 16 + quad * 4 + r;
                float v = acc[mi][ni][r] + bv;
                v = v > 0.f ? v : 0.f;
                const bf16 hi = f2b(v);
                const bf16 lo = f2b(v - b2f(hi));
                bf16* o = out + (size_t)row * 1536 + 3 * col;
                o[0] = hi; o[1] = hi; o[2] = lo;
            }
        }
}

// ---------------------------------------------------------------------------
// Generic bf16 MFMA GEMM. EPI: 0 = f32 out; 1 = split3 bf16 (hi,hi,lo, ldc=3N);
// 2 = bf16 out; 3 = f32 out with clip[-1,1].  Grid: (N/128, M/128).
// ---------------------------------------------------------------------------
template <int EPI, int RELU>
__global__ __launch_bounds__(256)
void gemm_bt(const bf16* __restrict__ A, const bf16* __restrict__ Bt,
             const float* __restrict__ bias, void* __restrict__ outp,
             int M, int N, int K)
{
    __shared__ bf16 As[128 * 64];
    __shared__ bf16 Bs[128 * 64];
    const int t = threadIdx.x, lane = t & 63, w = t >> 6;
    const int n0 = blockIdx.x * 128;
    const int m0 = blockIdx.y * 128;
    const int wr = w >> 1, wc = w & 1, l15 = lane & 15, quad = lane >> 4;

    f32x4 acc[4][4];
    #pragma unroll
    for (int i = 0; i < 4; ++i)
        #pragma unroll
        for (int j = 0; j < 4; ++j)
            #pragma unroll
            for (int r = 0; r < 4; ++r) acc[i][j][r] = 0.f;

    for (int k0 = 0; k0 < K; k0 += 64) {
        #pragma unroll
        for (int i = 0; i < 4; ++i) {
            const int c   = i * 256 + t;
            const int row = c >> 3;
            const int col = (c & 7) * 8;
            const bf16* ga = A  + (size_t)(m0 + row) * K + k0 + col;
            const bf16* gb = Bt + (size_t)(n0 + row) * K + k0 + col;
            __builtin_amdgcn_global_load_lds(
                (const __attribute__((address_space(1))) void*)ga,
                (__attribute__((address_space(3))) void*)(As + (size_t)c * 8), 16, 0, 0);
            __builtin_amdgcn_global_load_lds(
                (const __attribute__((address_space(1))) void*)gb,
                (__attribute__((address_space(3))) void*)(Bs + (size_t)c * 8), 16, 0, 0);
        }
        __syncthreads();
        #pragma unroll
        for (int kk = 0; kk < 2; ++kk) {
            bf16x8 af[4], bfr[4];
            #pragma unroll
            for (int mi = 0; mi < 4; ++mi)
                af[mi] = *(const bf16x8*)(As + (wr * 64 + mi * 16 + l15) * 64 + kk * 32 + quad * 8);
            #pragma unroll
            for (int ni = 0; ni < 4; ++ni)
                bfr[ni] = *(const bf16x8*)(Bs + (wc * 64 + ni * 16 + l15) * 64 + kk * 32 + quad * 8);
            #pragma unroll
            for (int mi = 0; mi < 4; ++mi)
                #pragma unroll
                for (int ni = 0; ni < 4; ++ni)
                    acc[mi][ni] = __builtin_amdgcn_mfma_f32_16x16x32_bf16(
                        af[mi], bfr[ni], acc[mi][ni], 0, 0, 0);
        }
        __syncthreads();
    }

    #pragma unroll
    for (int mi = 0; mi < 4; ++mi)
        #pragma unroll
        for (int ni = 0; ni < 4; ++ni) {
            const int col = n0 + wc * 64 + ni * 16 + l15;
            const float bv = bias[col];
            #pragma unroll
            for (int r = 0; r < 4; ++r) {
                const int row = m0 + wr * 64 + mi * 16 + quad * 4 + r;
                float v = acc[mi][ni][r] + bv;
                if (RELU) v = v > 0.f ? v : 0.f;
                if (EPI == 0) {
                    ((float*)outp)[(size_t)row * N + col] = v;
                } else if (EPI == 1) {
                    const bf16 hi = f2b(v);
                    const bf16 lo = f2b(v - b2f(hi));
                    bf16* o = (bf16*)outp + (size_t)row * 3 * N + 3 * col;
                    o[0] = hi; o[1] = hi; o[2] = lo;
                } else if (EPI == 2) {
                    ((bf16*)outp)[(size_t)row * N + col] = f2b(v);
                } else {
                    v = fminf(fmaxf(v, -1.f), 1.f);
                    ((float*)outp)[(size_t)row * N + col] = v;
                }
            }
        }
}

// ---------------------------------------------------------------------------
// VQ stage 2: one block per (expert, 128-row chunk). Codebook/Wout/cnorm/bout
// staged in LDS once. Per 4-row iter: thread==code distances (float4 LDS,
// pad-36 rows), u64-key shuffle argmin (first-min tie-break), gather+commit,
// qe = q@Wout+bout -> qemb. Grid 192 x 256.
// ---------------------------------------------------------------------------
__global__ __launch_bounds__(256)
void vq2_kernel(const float* __restrict__ xe_buf, const float* __restrict__ cb,
                const float* __restrict__ cnorm, const float* __restrict__ Wout,
                const float* __restrict__ bout, float* __restrict__ qemb,
                float* __restrict__ idx_out, float* __restrict__ commit_acc)
{
    __shared__ float cb_s[256 * 36];   // padded: row stride 36 (16B-aligned, uniform banks)
    __shared__ float wo_s[32 * 128];
    __shared__ float cn_s[256];
    __shared__ float bo_s[128];
    __shared__ float xe_s[4 * 32];
    __shared__ float q_s[4 * 32];
    __shared__ int   idx_s[4];
    __shared__ u64   wred[4][4];
    __shared__ float cred[256];

    const int e  = blockIdx.x >> 6;
    const int rb = blockIdx.x & 63;
    const int t = threadIdx.x, lane = t & 63, w = t >> 6;

    for (int j = t; j < 256 * 32; j += 256) {
        const int code = j >> 5, c = j & 31;
        cb_s[code * 36 + c] = cb[(size_t)e * 8192 + j];
    }
    for (int j = t; j < 4096; j += 256) wo_s[j] = Wout[(size_t)e * 4096 + j];
    cn_s[t] = cnorm[e * 256 + t];
    if (t < 128) bo_s[t] = bout[e * 128 + t];
    float commit_loc = 0.f;
    __syncthreads();

    for (int it = 0; it < 32; ++it) {
        const int r0 = rb * 128 + it * 4;
        if (t < 128) {
            const int r4 = t >> 5, c = t & 31;
            xe_s[r4 * 32 + c] = xe_buf[(size_t)(r0 + r4) * 128 + e * 32 + c];
        }
        __syncthreads();

        u64 key[4];
        {
            const float4* cp = (const float4*)(cb_s + t * 36);
            const float cn = cn_s[t];
            #pragma unroll
            for (int r4 = 0; r4 < 4; ++r4) {
                float dot = 0.f;
                #pragma unroll
                for (int c4 = 0; c4 < 8; ++c4) {
                    const float4 cv = cp[c4];
                    const float4 xv = *(const float4*)(xe_s + r4 * 32 + c4 * 4);
                    dot += xv.x * cv.x + xv.y * cv.y + xv.z * cv.z + xv.w * cv.w;
                }
                const float d = cn - 2.f * dot;
                u32 ub = __builtin_bit_cast(u32, d);
                ub = (ub & 0x80000000u) ? ~ub : (ub | 0x80000000u);
                key[r4] = ((u64)ub << 32) | (u32)t;
            }
        }
        #pragma unroll
        for (int off = 32; off; off >>= 1) {
            #pragma unroll
            for (int r4 = 0; r4 < 4; ++r4) {
                const u64 o = __shfl_down(key[r4], off, 64);
                if (o < key[r4]) key[r4] = o;
            }
        }
        if (lane == 0) {
            #pragma unroll
            for (int r4 = 0; r4 < 4; ++r4) wred[r4][w] = key[r4];
        }
        __syncthreads();
        if (t < 4) {
            u64 k = wred[t][0];
            #pragma unroll
            for (int ww = 1; ww < 4; ++ww) if (wred[t][ww] < k) k = wred[t][ww];
            const int code = (int)(k & 0xFFFFFFFFu);
            idx_s[t] = code;
            idx_out[(size_t)(r0 + t) * 3 + e] = (float)code;
        }
        __syncthreads();
        if (t < 128) {
            const int r4 = t >> 5, c = t & 31;
            const float q = cb_s[idx_s[r4] * 36 + c];
            q_s[r4 * 32 + c] = q;
            const float dd = q - xe_s[r4 * 32 + c];
            commit_loc += dd * dd;
        }
        __syncthreads();
        #pragma unroll
        for (int p = 0; p < 2; ++p) {
            const int j = p * 256 + t;
            const int r4 = j >> 7, h = j & 127;
            float s = bo_s[h];
            #pragma unroll
            for (int c = 0; c < 32; ++c) s += q_s[r4 * 32 + c] * wo_s[c * 128 + h];
            qemb[((size_t)e * 8192 + r0 + r4) * 128 + h] = s;
        }
        __syncthreads();
    }

    cred[t] = commit_loc;
    __syncthreads();
    for (int o = 128; o; o >>= 1) { if (t < o) cred[t] += cred[t + o]; __syncthreads(); }
    if (t == 0) atomicAdd(commit_acc, cred[0]);
}

// ---------------------------------------------------------------------------
// rl = mean_e qemb (bf16) + per-h expert sums for the decorrelation mean.
// Grid 32 x 256 (256 rows per block).
// ---------------------------------------------------------------------------
__global__ __launch_bounds__(256)
void rlmean_kernel(const float* __restrict__ qemb, bf16* __restrict__ rl,
                   float* __restrict__ meanAcc)
{
    const int t = threadIdx.x, h = t & 127, half = t >> 7;
    const int r0 = blockIdx.x * 256;
    float a0 = 0.f, a1 = 0.f, a2 = 0.f;
    for (int r = r0 + half; r < r0 + 256; r += 2) {
        const float v0 = qemb[((size_t)0 * 8192 + r) * 128 + h];
        const float v1 = qemb[((size_t)1 * 8192 + r) * 128 + h];
        const float v2 = qemb[((size_t)2 * 8192 + r) * 128 + h];
        a0 += v0; a1 += v1; a2 += v2;
        rl[(size_t)r * 128 + h] = f2b((v0 + v1 + v2) * (1.f / 3.f));
    }
    __shared__ float red[3][256];
    red[0][t] = a0; red[1][t] = a1; red[2][t] = a2;
    __syncthreads();
    if (t < 128) {
        atomicAdd(&meanAcc[0 * 128 + h], red[0][t] + red[0][t + 128]);
        atomicAdd(&meanAcc[1 * 128 + h], red[1][t] + red[1][t + 128]);
        atomicAdd(&meanAcc[2 * 128 + h], red[2][t] + red[2][t + 128]);
    }
}

__global__ __launch_bounds__(256)
void gram_kernel(const float* __restrict__ qemb, const float* __restrict__ meanAcc,
                 double* __restrict__ gram)
{
    const int t = threadIdx.x;
    const int h = t & 127, half = t >> 7;
    const int b0 = blockIdx.x * 128;
    const float m0 = meanAcc[0 * 128 + h] * (1.f / 8192.f);
    const float m1 = meanAcc[1 * 128 + h] * (1.f / 8192.f);
    const float m2 = meanAcc[2 * 128 + h] * (1.f / 8192.f);
    float g[6] = {0, 0, 0, 0, 0, 0};
    for (int b = b0 + half; b < b0 + 128; b += 2) {
        const float v0 = qemb[((size_t)0 * 8192 + b) * 128 + h] - m0;
        const float v1 = qemb[((size_t)1 * 8192 + b) * 128 + h] - m1;
        const float v2 = qemb[((size_t)2 * 8192 + b) * 128 + h] - m2;
        g[0] += v0 * v0; g[1] += v0 * v1; g[2] += v0 * v2;
        g[3] += v1 * v1; g[4] += v1 * v2; g[5] += v2 * v2;
    }
    __shared__ float red[256];
    for (int i = 0; i < 6; ++i) {
        red[t] = g[i];
        __syncthreads();
        for (int o = 128; o; o >>= 1) { if (t < o) red[t] += red[t + o]; __syncthreads(); }
        if (t == 0) atomicAdd(&gram[i], (double)red[0]);
        __syncthreads();
    }
}

__global__ void final_kernel(const float* __restrict__ commit_acc,
                             const double* __restrict__ gram,
                             float* __restrict__ out2)
{
    if (threadIdx.x != 0 || blockIdx.x != 0) return;
    const double denom = 8192.0 * 128.0 - 1.0;
    const double c00 = gram[0] / denom, c01 = gram[1] / denom, c02 = gram[2] / denom;
    const double c11 = gram[3] / denom, c12 = gram[4] / denom, c22 = gram[5] / denom;
    double s0 = sqrt(c00), s1 = sqrt(c11), s2 = sqrt(c22);
    if (!(s0 > 1e-8)) s0 = 1.0;
    if (!(s1 > 1e-8)) s1 = 1.0;
    if (!(s2 > 1e-8)) s2 = 1.0;
    const double r01 = c01 / (s0 * s1), r02 = c02 / (s0 * s2), r12 = c12 / (s1 * s2);
    const double decorr = 2.0 * (r01 * r01 + r02 * r02 + r12 * r12);
    out2[0] = (float)((double)commit_acc[0] * (0.25 / (8192.0 * 32.0)));
    out2[1] = (float)decorr;
}

// ---------------------------------------------------------------------------
extern "C" void kernel_launch(void* const* d_in, const int* in_sizes, int n_in,
                              void* d_out, int out_size, void* d_ws, size_t ws_size,
                              hipStream_t stream)
{
    const float* x    = (const float*)d_in[0];
    const float* Wd1  = (const float*)d_in[1];
    const float* bd1  = (const float*)d_in[2];
    const float* Wd2  = (const float*)d_in[3];
    const float* bd2  = (const float*)d_in[4];
    const float* Wd3  = (const float*)d_in[5];
    const float* bd3  = (const float*)d_in[6];
    const float* Win  = (const float*)d_in[7];
    const float* bin_ = (const float*)d_in[8];
    const float* cb   = (const float*)d_in[9];
    const float* Wout = (const float*)d_in[10];
    const float* bout = (const float*)d_in[11];
    const float* Wu1  = (const float*)d_in[12];
    const float* bu1  = (const float*)d_in[13];
    const float* Wu2  = (const float*)d_in[14];
    const float* bu2  = (const float*)d_in[15];
    const float* Wu3  = (const float*)d_in[16];
    const float* bu3  = (const float*)d_in[17];

    char* ws = (char*)d_ws;
    bf16*  Wd1s   = (bf16*)(ws + OFF_WD1S);
    bf16*  Wd2s   = (bf16*)(ws + OFF_WD2S);
    bf16*  WfuseS = (bf16*)(ws + OFF_WFUS);
    bf16*  Wu1T   = (bf16*)(ws + OFF_WU1T);
    bf16*  Wu2T   = (bf16*)(ws + OFF_WU2T);
    bf16*  Wu3T   = (bf16*)(ws + OFF_WU3T);
    bf16*  h1s    = (bf16*)(ws + OFF_H1S);
    bf16*  h2s    = (bf16*)(ws + OFF_H2S);
    float* xe     = (float*)(ws + OFF_XE);
    float* qemb   = (float*)(ws + OFF_QEMB);
    bf16*  rl     = (bf16*)(ws + OFF_RL);
    bf16*  u1     = (bf16*)(ws + OFF_U1);
    bf16*  u2     = (bf16*)(ws + OFF_U2);
    float* cnorm  = (float*)(ws + OFF_CNRM);
    float* bfuse  = (float*)(ws + OFF_BFUS);
    float* commit = (float*)(ws + OFF_STAT);
    double* gram  = (double*)(ws + OFF_STAT + 8);
    float* meanA  = (float*)(ws + OFF_STAT + 64);

    float* out_f   = (float*)d_out;
    float* idx_out = out_f + (size_t)8192 * 4096;
    float* scal    = idx_out + (size_t)8192 * 3;

    hipMemsetAsync(ws + OFF_STAT, 0, 2048, stream);

    const dim3 tb(32, 8);
    wtrans_split3<<<dim3(16, 128), tb, 0, stream>>>(Wd1, Wd1s, 4096, 512);
    wtrans_split3<<<dim3(8, 16),   tb, 0, stream>>>(Wd2, Wd2s, 512, 256);
    wtrans_bf16<<<dim3(8, 4),      tb, 0, stream>>>(Wu1, Wu1T, 128, 256);
    wtrans_bf16<<<dim3(16, 8),     tb, 0, stream>>>(Wu2, Wu2T, 256, 512);
    wtrans_bf16<<<dim3(128, 16),   tb, 0, stream>>>(Wu3, Wu3T, 512, 4096);
    cnorm_kernel<<<3, 256, 0, stream>>>(cb, cnorm);
    wfuse_kernel<<<128, 256, 0, stream>>>(Wd3, bd3, Win, bin_, WfuseS, bfuse);

    // down MLP (split bf16, ~f32 accuracy) ending directly in xe = latent@Win+...
    gemm1_x3<<<dim3(4, 64), 256, 0, stream>>>(x, Wd1s, bd1, h1s);
    gemm_bt<1, 1><<<dim3(2, 64), 256, 0, stream>>>(h1s, Wd2s, bd2, h2s, 8192, 256, 1536);
    gemm_bt<0, 0><<<dim3(1, 64), 256, 0, stream>>>(h2s, WfuseS, bfuse, xe, 8192, 128, 768);

    vq2_kernel<<<192, 256, 0, stream>>>(xe, cb, cnorm, Wout, bout, qemb, idx_out, commit);
    rlmean_kernel<<<32, 256, 0, stream>>>(qemb, rl, meanA);
    gram_kernel<<<64, 256, 0, stream>>>(qemb, meanA, gram);
    final_kernel<<<1, 64, 0, stream>>>(commit, gram, scal);

    // up MLP: plain bf16 compute, f32 recon out
    gemm_bt<2, 1><<<dim3(2, 64),  256, 0, stream>>>(rl, Wu1T, bu1, u1,    8192, 256,  128);
    gemm_bt<2, 1><<<dim3(4, 64),  256, 0, stream>>>(u1, Wu2T, bu2, u2,    8192, 512,  256);
    gemm_bt<3, 0><<<dim3(32, 64), 256, 0, stream>>>(u2, Wu3T, bu3, out_f, 8192, 4096, 512);

    (void)in_sizes; (void)n_in; (void)out_size; (void)ws_size;
}